// Round 1
// baseline (57.142 us; speedup 1.0000x reference)
//
#include <hip/hip_runtime.h>

// Problem constants (match reference)
#define BDIM 4096
#define LDIM 128
#define FDIM 64
#define NVALS 129   // counts range 0..128

// ---------------------------------------------------------------------------
// Kernel 1: build lookup table T[v][g] = sum_f relu(v*W1[f]+b1[f]) * W2[f][g] + b2[g]
// feat(pos) = T[self_cnt] + T[cross_cnt]  (masked pos -> T[0]+T[0], which equals
// the reference's encode of freq=(0,0): 2*(relu(b1)@W2 + b2)).
// grid = 129 blocks, block = 64 threads (one wave).
// ---------------------------------------------------------------------------
__global__ __launch_bounds__(FDIM) void build_table_kernel(
    const float* __restrict__ W1, const float* __restrict__ b1,
    const float* __restrict__ W2, const float* __restrict__ b2,
    float* __restrict__ T)
{
    const int v = blockIdx.x;    // count value 0..128
    const int g = threadIdx.x;   // output feature 0..63

    __shared__ float h[FDIM];
    h[g] = fmaxf((float)v * W1[g] + b1[g], 0.0f);   // relu(v*W1[f]+b1[f])
    __syncthreads();

    float acc = b2[g];
#pragma unroll
    for (int f = 0; f < FDIM; ++f)
        acc = fmaf(h[f], W2[f * FDIM + g], acc);    // W2 is [F,F] row-major: W2[f][g]

    T[v * FDIM + g] = acc;
}

// ---------------------------------------------------------------------------
// Kernel 2: one block per batch row. 256 threads.
//   Phase A: stage src/dst ids in LDS.
//   Phase B: threads 0..127 count for src positions, 128..255 for dst positions
//            (128-iter LDS-broadcast compare loop, uniform control flow).
//   Phase C: all 256 threads stream the 2x128x64 f32 outputs as float4,
//            gathering T[a]+T[b] (table is L1/L2-hot, 33 KB).
// ---------------------------------------------------------------------------
__global__ __launch_bounds__(256) void encode_rows_kernel(
    const int* __restrict__ src, const int* __restrict__ dst,
    const float* __restrict__ T,
    float* __restrict__ out_src, float* __restrict__ out_dst)
{
    const int b = blockIdx.x;
    const int t = threadIdx.x;

    __shared__ int sID[LDIM], dID[LDIM];
    __shared__ int aS[LDIM], bS[LDIM], aD[LDIM], bD[LDIM];

    // Phase A: load ids (coalesced, 128 ints each side)
    if (t < LDIM) sID[t] = src[(size_t)b * LDIM + t];
    else          dID[t - LDIM] = dst[(size_t)b * LDIM + (t - LDIM)];
    __syncthreads();

    // Phase B: equality counting. Same j for all lanes -> LDS broadcast, no conflict.
    if (t < LDIM) {
        const int id = sID[t];
        int a = 0, c = 0;
#pragma unroll 8
        for (int j = 0; j < LDIM; ++j) {
            a += (sID[j] == id);
            c += (dID[j] == id);
        }
        if (id == 0) { a = 0; c = 0; }   // padding mask -> freq (0,0)
        aS[t] = a; bS[t] = c;
    } else {
        const int id = dID[t - LDIM];
        int a = 0, c = 0;
#pragma unroll 8
        for (int j = 0; j < LDIM; ++j) {
            a += (dID[j] == id);
            c += (sID[j] == id);
        }
        if (id == 0) { a = 0; c = 0; }
        aD[t - LDIM] = a; bD[t - LDIM] = c;
    }
    __syncthreads();

    // Phase C: write 128 positions x 64 floats = 2048 float4 per side.
    const float4* __restrict__ T4 = (const float4*)T;      // T4[v*16 + chunk]
    float4* __restrict__ o4s = (float4*)out_src;
    float4* __restrict__ o4d = (float4*)out_dst;
    const size_t rowBase = (size_t)b * (LDIM * FDIM / 4);  // 2048 float4 per row

#pragma unroll
    for (int k = 0; k < 8; ++k) {
        const int c   = t + k * 256;     // 0..2047
        const int pos = c >> 4;          // position within row
        const int ch  = c & 15;          // float4 chunk within the 64-float feature

        {
            const float4 va = T4[aS[pos] * 16 + ch];
            const float4 vb = T4[bS[pos] * 16 + ch];
            float4 r;
            r.x = va.x + vb.x; r.y = va.y + vb.y;
            r.z = va.z + vb.z; r.w = va.w + vb.w;
            o4s[rowBase + c] = r;
        }
        {
            const float4 va = T4[aD[pos] * 16 + ch];
            const float4 vb = T4[bD[pos] * 16 + ch];
            float4 r;
            r.x = va.x + vb.x; r.y = va.y + vb.y;
            r.z = va.z + vb.z; r.w = va.w + vb.w;
            o4d[rowBase + c] = r;
        }
    }
}

extern "C" void kernel_launch(void* const* d_in, const int* in_sizes, int n_in,
                              void* d_out, int out_size, void* d_ws, size_t ws_size,
                              hipStream_t stream)
{
    const int*   src = (const int*)d_in[0];    // int64 in ref -> int32 from harness
    const int*   dst = (const int*)d_in[1];
    const float* W1  = (const float*)d_in[2];  // [1,F]
    const float* b1  = (const float*)d_in[3];  // [F]
    const float* W2  = (const float*)d_in[4];  // [F,F]
    const float* b2  = (const float*)d_in[5];  // [F]

    float* out = (float*)d_out;                // [src_feat | dst_feat], each B*L*F f32
    float* T   = (float*)d_ws;                 // 129*64 f32 = 33 KB lookup table

    const int B = in_sizes[0] / LDIM;          // 4096
    const size_t half = (size_t)B * LDIM * FDIM;

    build_table_kernel<<<NVALS, FDIM, 0, stream>>>(W1, b1, W2, b2, T);
    encode_rows_kernel<<<B, 256, 0, stream>>>(src, dst, T, out, out + half);
}